// Round 4
// baseline (182.446 us; speedup 1.0000x reference)
//
#include <hip/hip_runtime.h>

#define BB 8
#define TT 2048
#define CC 1024
#define HH 64
#define MM (BB * TT)   // 16384 rows

typedef _Float16 half8 __attribute__((ext_vector_type(8)));
typedef _Float16 half4 __attribute__((ext_vector_type(4)));
typedef float floatx4 __attribute__((ext_vector_type(4)));

// 16-lane all-reduce max via DPP row-rotate butterfly (VALU pipe, no LDS).
template <int CTRL>
__device__ __forceinline__ float dpp_max_step(float x)
{
    union { float f; int i; } u, v;
    u.f = x;
    v.i = __builtin_amdgcn_update_dpp(u.i, u.i, CTRL, 0xf, 0xf, false);
    return fmaxf(x, v.f);
}
__device__ __forceinline__ float rowmax16(float x)
{
    x = dpp_max_step<0x128>(x);   // ROW_ROR:8
    x = dpp_max_step<0x124>(x);   // ROW_ROR:4
    x = dpp_max_step<0x122>(x);   // ROW_ROR:2
    x = dpp_max_step<0x121>(x);   // ROW_ROR:1
    return x;
}

// ---------------------------------------------------------------------------
// Kernel 0: pack W -> fp16 W16[192][1024]; rows 0..63 = Wq * 8 (sqrt(H) fold),
// 64..127 = Wk, 128..191 = Wv.
// ---------------------------------------------------------------------------
__global__ __launch_bounds__(256)
void w_convert(const float* __restrict__ Wk, const float* __restrict__ Wq,
               const float* __restrict__ Wv, _Float16* __restrict__ W16)
{
    const int e = (blockIdx.x * 256 + threadIdx.x) * 8;
    const int row = e >> 10;            // 0..191
    const int c   = e & 1023;
    const int which = row >> 6;
    const float* __restrict__ src = (which == 0) ? Wq : ((which == 1) ? Wk : Wv);
    const float scale = (which == 0) ? 8.0f : 1.0f;
    const int srow = row & 63;
    const float4 a = *reinterpret_cast<const float4*>(&src[srow * 1024 + c]);
    const float4 b = *reinterpret_cast<const float4*>(&src[srow * 1024 + c + 4]);
    const half8 o = { (_Float16)(a.x * scale), (_Float16)(a.y * scale),
                      (_Float16)(a.z * scale), (_Float16)(a.w * scale),
                      (_Float16)(b.x * scale), (_Float16)(b.y * scale),
                      (_Float16)(b.z * scale), (_Float16)(b.w * scale) };
    *reinterpret_cast<half8*>(&W16[e]) = o;
}

// ---------------------------------------------------------------------------
// Kernel 1: barrier-free QKV projection, direct global->fragment loads.
// Wave = 16-row M-tile x all 192 out cols (12 n-frags). 1024 waves total,
// grid 256 x 256 (4 waves/block, no LDS, no syncthreads). B-frags come from
// L2-hot W16; A-frags from x (read exactly once chip-wide -> HBM floor).
// Depth-1 software pipeline (two register sets, no copies).
// V output written pre-transposed: vt16[b][h][t].
// ---------------------------------------------------------------------------
__device__ __forceinline__ void qkv_loadA(const float* __restrict__ xrow, int k0,
                                          float4& xa, float4& xb)
{
    xa = *reinterpret_cast<const float4*>(xrow + k0);
    xb = *reinterpret_cast<const float4*>(xrow + k0 + 4);
}
__device__ __forceinline__ void qkv_loadB(const _Float16* __restrict__ wbase, int k0,
                                          half8 (&bf)[12])
{
    #pragma unroll
    for (int n = 0; n < 12; ++n)
        bf[n] = *reinterpret_cast<const half8*>(wbase + (size_t)n * 16 * CC + k0);
}
__device__ __forceinline__ void qkv_mfma(const float4& xa, const float4& xb,
                                         const half8 (&bf)[12], floatx4 (&acc)[12])
{
    const half8 af = { (_Float16)xa.x, (_Float16)xa.y, (_Float16)xa.z, (_Float16)xa.w,
                       (_Float16)xb.x, (_Float16)xb.y, (_Float16)xb.z, (_Float16)xb.w };
    #pragma unroll
    for (int n = 0; n < 12; ++n)
        acc[n] = __builtin_amdgcn_mfma_f32_16x16x32_f16(af, bf[n], acc[n], 0, 0, 0);
}

__global__ __launch_bounds__(256, 1)
void qkv_direct(const float* __restrict__ x, const _Float16* __restrict__ W16,
                _Float16* __restrict__ q16, _Float16* __restrict__ k16,
                _Float16* __restrict__ vt16)
{
    const int tid  = threadIdx.x;
    const int lane = tid & 63;
    const int wv   = tid >> 6;
    const int tile = blockIdx.x * 4 + wv;   // 0..1023
    const int m_base = tile * 16;
    const int fm = lane & 15;
    const int fq = lane >> 4;
    const int fk = fq * 8;
    const int fr = fq * 4;

    const float*     __restrict__ xrow  = &x[(size_t)(m_base + fm) * CC + fk];
    const _Float16*  __restrict__ wbase = &W16[(size_t)fm * CC + fk];

    floatx4 acc[12];
    #pragma unroll
    for (int n = 0; n < 12; ++n)
        #pragma unroll
        for (int r = 0; r < 4; ++r) acc[n][r] = 0.0f;

    float4 xa0, xb0, xa1, xb1;
    half8 bf0[12], bf1[12];

    qkv_loadA(xrow, 0, xa0, xb0);
    qkv_loadB(wbase, 0, bf0);

    #pragma unroll 2
    for (int c = 0; c < 32; c += 2) {
        qkv_loadA(xrow, (c + 1) * 32, xa1, xb1);
        qkv_loadB(wbase, (c + 1) * 32, bf1);
        qkv_mfma(xa0, xb0, bf0, acc);
        if (c + 2 < 32) {
            qkv_loadA(xrow, (c + 2) * 32, xa0, xb0);
            qkv_loadB(wbase, (c + 2) * 32, bf0);
        }
        qkv_mfma(xa1, xb1, bf1, acc);
    }

    // epilogue
    const int b  = m_base >> 11;        // row / 2048
    const int t0 = m_base & 2047;
    #pragma unroll
    for (int n = 0; n < 12; ++n) {
        const int col = n * 16 + fm;
        if (n < 8) {                    // q (cols 0..63) or k (64..127)
            _Float16* __restrict__ dst = (n < 4) ? q16 : k16;
            const int h = col & 63;
            #pragma unroll
            for (int r = 0; r < 4; ++r)
                dst[(size_t)(m_base + fr + r) * HH + h] = (_Float16)acc[n][r];
        } else {                        // v -> transposed
            const int h = col - 128;
            const half4 pk = { (_Float16)acc[n][0], (_Float16)acc[n][1],
                               (_Float16)acc[n][2], (_Float16)acc[n][3] };
            *reinterpret_cast<half4*>(
                &vt16[((size_t)b * HH + h) * TT + t0 + fr]) = pk;
        }
    }
}

// ---------------------------------------------------------------------------
// Kernel 2: fused causal attention, fp16 MFMA, online softmax.
// grid 512 = 8 batches x 64 q-tiles of 32 rows. it mapping pairs long+short
// tiles on the same CU (g<32 -> 63-g, else g-32): every CU sums to 64 j-steps.
// Softmax: row-max via DPP butterfly (VALU), row-sum via ones-MFMA (lacc).
// No __shfl anywhere in the loop.
// ---------------------------------------------------------------------------
__global__ __launch_bounds__(128, 3)
void attn(const _Float16* __restrict__ q16, const _Float16* __restrict__ k16,
          const _Float16* __restrict__ vt16, float* __restrict__ out)
{
    __shared__ _Float16 Ks[64 * 72];
    __shared__ _Float16 Vts[64 * 72];
    __shared__ _Float16 Ps[2 * 16 * 72];

    const int bid = blockIdx.x;
    const int b = bid & 7;
    const int g = bid >> 3;                 // 0..63
    const int it = (g < 32) ? (63 - g) : (g - 32);
    const int tid  = threadIdx.x;
    const int lane = tid & 63;
    const int wv   = tid >> 6;              // 0,1
    const int fm   = lane & 15;
    const int fk   = (lane >> 4) * 8;
    const int fr   = (lane >> 4) * 4;

    const _Float16* __restrict__ qb  = q16  + (size_t)b * TT * HH;
    const _Float16* __restrict__ kb  = k16  + (size_t)b * TT * HH;
    const _Float16* __restrict__ vtb = vt16 + (size_t)b * HH * TT;

    const int qrow = it * 32 + wv * 16 + fm;
    const half8 qf0 = *reinterpret_cast<const half8*>(&qb[(size_t)qrow * HH + fk]);
    const half8 qf1 = *reinterpret_cast<const half8*>(&qb[(size_t)qrow * HH + 32 + fk]);

    floatx4 O[4], lacc;
    float m_r[4];
    #pragma unroll
    for (int r = 0; r < 4; ++r) {
        m_r[r] = -3.0e38f;
        lacc[r] = 0.0f;
        #pragma unroll
        for (int ht = 0; ht < 4; ++ht) O[ht][r] = 0.0f;
    }

    const half8 ones = { (_Float16)1.f, (_Float16)1.f, (_Float16)1.f, (_Float16)1.f,
                         (_Float16)1.f, (_Float16)1.f, (_Float16)1.f, (_Float16)1.f };

    const int Ji = (it >> 1) + 1;
    const int sr = tid >> 3;          // 0..15
    const int sc = (tid & 7) * 8;     // 0..56

    half8 kr[4], vr[4];
    #pragma unroll
    for (int i = 0; i < 4; ++i) {
        kr[i] = *reinterpret_cast<const half8*>(&kb[(size_t)(sr + i * 16) * HH + sc]);
        vr[i] = *reinterpret_cast<const half8*>(&vtb[(size_t)(sr + i * 16) * TT + sc]);
    }

    for (int j = 0; j < Ji; ++j) {
        __syncthreads();   // prior iteration's LDS reads complete
        #pragma unroll
        for (int i = 0; i < 4; ++i) {
            *reinterpret_cast<half8*>(&Ks[(sr + i * 16) * 72 + sc])  = kr[i];
            *reinterpret_cast<half8*>(&Vts[(sr + i * 16) * 72 + sc]) = vr[i];
        }
        __syncthreads();

        if (j + 1 < Ji) {
            const int jn = (j + 1) * 64;
            #pragma unroll
            for (int i = 0; i < 4; ++i) {
                kr[i] = *reinterpret_cast<const half8*>(&kb[(size_t)(jn + sr + i * 16) * HH + sc]);
                vr[i] = *reinterpret_cast<const half8*>(&vtb[(size_t)(sr + i * 16) * TT + jn + sc]);
            }
        }

        // ---- S = Q K^T : 8 MFMAs ----
        floatx4 sa[4];
        #pragma unroll
        for (int nt = 0; nt < 4; ++nt) {
            #pragma unroll
            for (int r = 0; r < 4; ++r) sa[nt][r] = 0.0f;
            const _Float16* kp = &Ks[(nt * 16 + fm) * 72];
            const half8 b0 = *reinterpret_cast<const half8*>(kp + fk);
            const half8 b1 = *reinterpret_cast<const half8*>(kp + 32 + fk);
            sa[nt] = __builtin_amdgcn_mfma_f32_16x16x32_f16(qf0, b0, sa[nt], 0, 0, 0);
            sa[nt] = __builtin_amdgcn_mfma_f32_16x16x32_f16(qf1, b1, sa[nt], 0, 0, 0);
        }

        // ---- causal mask (only diagonal j-tile) ----
        if (j == Ji - 1) {
            const int rbase = it * 32 + wv * 16 + fr;
            #pragma unroll
            for (int nt = 0; nt < 4; ++nt) {
                const int col = j * 64 + nt * 16 + fm;
                #pragma unroll
                for (int r = 0; r < 4; ++r)
                    if (col > rbase + r) sa[nt][r] = -3.0e38f;
            }
        }

        // ---- online softmax: DPP max, no sum (ones-MFMA handles l) ----
        #pragma unroll
        for (int r = 0; r < 4; ++r) {
            float mx = fmaxf(fmaxf(sa[0][r], sa[1][r]), fmaxf(sa[2][r], sa[3][r]));
            mx = rowmax16(mx);
            const float mn = fmaxf(m_r[r], mx);
            const float alpha = __expf(m_r[r] - mn);
            m_r[r] = mn;
            _Float16* pp = &Ps[wv * 1152 + (fr + r) * 72 + fm];
            pp[0]  = (_Float16)__expf(sa[0][r] - mn);
            pp[16] = (_Float16)__expf(sa[1][r] - mn);
            pp[32] = (_Float16)__expf(sa[2][r] - mn);
            pp[48] = (_Float16)__expf(sa[3][r] - mn);
            lacc[r] *= alpha;
            O[0][r] *= alpha; O[1][r] *= alpha; O[2][r] *= alpha; O[3][r] *= alpha;
        }
        __syncthreads();   // Ps visible before A-frag reads

        // ---- O += P V, l += P 1 : 10 MFMAs ----
        #pragma unroll
        for (int ch = 0; ch < 2; ++ch) {
            const half8 pa = *reinterpret_cast<const half8*>(
                &Ps[wv * 1152 + fm * 72 + ch * 32 + fk]);
            lacc = __builtin_amdgcn_mfma_f32_16x16x32_f16(pa, ones, lacc, 0, 0, 0);
            #pragma unroll
            for (int ht = 0; ht < 4; ++ht) {
                const half8 vb = *reinterpret_cast<const half8*>(
                    &Vts[(ht * 16 + fm) * 72 + ch * 32 + fk]);
                O[ht] = __builtin_amdgcn_mfma_f32_16x16x32_f16(pa, vb, O[ht], 0, 0, 0);
            }
        }
    }

    // ---- epilogue: out = O / l ----
    #pragma unroll
    for (int r = 0; r < 4; ++r) {
        const float inv = 1.0f / lacc[r];
        const size_t rowoff = (size_t)(b * TT + it * 32 + wv * 16 + fr + r) * HH;
        #pragma unroll
        for (int ht = 0; ht < 4; ++ht)
            out[rowoff + ht * 16 + fm] = O[ht][r] * inv;
    }
}

// ---------------------------------------------------------------------------
extern "C" void kernel_launch(void* const* d_in, const int* in_sizes, int n_in,
                              void* d_out, int out_size, void* d_ws, size_t ws_size,
                              hipStream_t stream)
{
    (void)in_sizes; (void)n_in; (void)out_size; (void)ws_size;

    const float* x  = (const float*)d_in[0];
    const float* Wk = (const float*)d_in[1];
    const float* Wq = (const float*)d_in[2];
    const float* Wv = (const float*)d_in[3];
    float* out = (float*)d_out;

    _Float16* q16  = (_Float16*)d_ws;                     // [MM][HH]
    _Float16* k16  = q16 + (size_t)MM * HH;               // [MM][HH]
    _Float16* vt16 = k16 + (size_t)MM * HH;               // [BB][HH][TT]
    _Float16* W16  = vt16 + (size_t)MM * HH;              // [192][1024]

    w_convert<<<dim3(96), dim3(256), 0, stream>>>(Wk, Wq, Wv, W16);
    qkv_direct<<<dim3(256), dim3(256), 0, stream>>>(x, W16, q16, k16, vt16);
    attn<<<dim3(512), dim3(128), 0, stream>>>(q16, k16, vt16, out);
}